// Round 4
// baseline (151.535 us; speedup 1.0000x reference)
//
#include <hip/hip_runtime.h>

#define N_PTS   1024
#define IMG_H   128
#define IMG_W   128
#define NPIX    (IMG_H * IMG_W)
#define NEAR    0.01f
#define COV_BLUR 0.3f
#define NCHUNK  32
#define CHUNK_SZ (N_PTS / NCHUNK)     // 32 gaussians per chunk
#define PT_STRIDE 12                  // floats per point record (3 x float4)
#define PXS     4                     // pixels per thread (rows 32 apart)
#define ROWSTEP (NPIX / PXS)          // 4096
#define CBLK    256                   // composite block size (measured best, r4)
#define NSTRIP  (ROWSTEP / CBLK)      // 16 strips x 32 chunks = 512 blocks
#define NBLK    (NSTRIP * NCHUNK)     // 512 = exactly 2 blocks/CU, co-resident
#define NCOMB   (NPIX / 256)          // 64 combine blocks

// conic pre-scale: q' = -q/(2 ln2)  ->  exp(-q/2) == exp2(q'); 3-sigma: q' >= QLIM
#define S_SCALE (-0.72134752044448170368f)
#define QLIM    (-6.49212768400033533312f)

// ---------------------------------------------------------------------------
// Kernel 1: fused preprocess + stable depth sort (R1 body, proven).  Also
// zeroes the grid-arrival counter used by kernel 2 (kernel-boundary
// coherence makes the zero visible to the next dispatch; re-done every
// iteration since the harness re-poisons the workspace).
// Record (alpha folded into exponent):
//   A=[tz, u, v, ca'] B=[2cb', cc', qlim, colR] C=[colG, colB, log2a, 0]
// ---------------------------------------------------------------------------
__global__ __launch_bounds__(256) void k_sortpre(
    const float* __restrict__ coords,
    const float* __restrict__ covs,
    const float* __restrict__ colors,
    const float* __restrict__ alphas,
    const float* __restrict__ Wm,
    const float* __restrict__ Km,
    float* __restrict__ sorted,
    unsigned int* __restrict__ ctr)
{
    __shared__ __align__(16) float scoord[N_PTS * 3];            // 12 KB
    __shared__ __align__(16) unsigned long long skey[N_PTS];     // 8 KB
    int tid = threadIdx.x;

    if (blockIdx.x == 0 && tid == 0) *ctr = 0u;    // reset arrival counter

    // stage all 1024x3 coords coalesced: 768 float4, 3 per thread
    {
        float4* sc4 = (float4*)scoord;
        const float4* g4 = (const float4*)coords;
        #pragma unroll
        for (int j = 0; j < 3; j++) sc4[tid + j * 256] = g4[tid + j * 256];
    }

    float R[3][3], tv[3];
    #pragma unroll
    for (int r = 0; r < 3; r++) {
        #pragma unroll
        for (int c = 0; c < 3; c++) R[r][c] = Wm[r * 4 + c];
        tv[r] = Wm[r * 4 + 3];
    }
    float fx = Km[0], fy = Km[4], cx = Km[2], cy = Km[5];

    __syncthreads();

    // all 1024 stable sort keys -> LDS (single source of truth for ordering)
    #pragma unroll
    for (int q = 0; q < 4; q++) {
        int j = tid + q * 256;
        float c0 = scoord[3 * j], c1 = scoord[3 * j + 1], c2 = scoord[3 * j + 2];
        float d = R[2][0] * c0 + R[2][1] * c1 + R[2][2] * c2 + tv[2];
        unsigned int b = __float_as_uint(d);
        b ^= ((unsigned int)((int)b >> 31)) | 0x80000000u;       // monotone map
        skey[j] = ((unsigned long long)b << 10) | (unsigned int)j;
    }
    __syncthreads();

    int i = blockIdx.x * 256 + tid;

    // issue all uncoalesced global loads NOW; latency hides under rank scan
    float S[3][3];
    #pragma unroll
    for (int r = 0; r < 3; r++)
        #pragma unroll
        for (int c = 0; c < 3; c++) S[r][c] = covs[i * 9 + r * 3 + c];
    float colR = colors[3 * i + 0];
    float colG = colors[3 * i + 1];
    float colB = colors[3 * i + 2];
    float aRaw = alphas[i];

    float c0 = scoord[3 * i], c1 = scoord[3 * i + 1], c2 = scoord[3 * i + 2];
    float tz = R[2][0] * c0 + R[2][1] * c1 + R[2][2] * c2 + tv[2];
    unsigned long long mykey = skey[i];

    // stable rank count: one u64 compare per element
    int rank = 0;
    const ulonglong2* sk2 = (const ulonglong2*)skey;
    #pragma unroll 16
    for (int jj = 0; jj < N_PTS / 2; jj++) {
        ulonglong2 k2 = sk2[jj];
        rank += (k2.x < mykey);
        rank += (k2.y < mykey);
    }

    // full preprocess for own point
    float tx = R[0][0] * c0 + R[0][1] * c1 + R[0][2] * c2 + tv[0];
    float ty = R[1][0] * c0 + R[1][1] * c1 + R[1][2] * c2 + tv[1];

    float invz = 1.0f / fmaxf(tz, NEAR);
    float u = fx * tx * invz + cx;
    float v = fy * ty * invz + cy;
    float J00 = fx * invz;
    float J02 = -fx * tx * invz * invz;
    float J11 = fy * invz;
    float J12 = -fy * ty * invz * invz;

    float M[3][3];
    #pragma unroll
    for (int r = 0; r < 3; r++)
        #pragma unroll
        for (int c = 0; c < 3; c++)
            M[r][c] = R[r][0] * S[0][c] + R[r][1] * S[1][c] + R[r][2] * S[2][c];
    float Sc[3][3];
    #pragma unroll
    for (int r = 0; r < 3; r++)
        #pragma unroll
        for (int c = 0; c < 3; c++)
            Sc[r][c] = M[r][0] * R[c][0] + M[r][1] * R[c][1] + M[r][2] * R[c][2];

    float js0_0 = J00 * Sc[0][0] + J02 * Sc[2][0];
    float js0_1 = J00 * Sc[0][1] + J02 * Sc[2][1];
    float js0_2 = J00 * Sc[0][2] + J02 * Sc[2][2];
    float js1_1 = J11 * Sc[1][1] + J12 * Sc[2][1];
    float js1_2 = J11 * Sc[1][2] + J12 * Sc[2][2];

    float s00 = J00 * js0_0 + J02 * js0_2 + COV_BLUR;
    float s01 = J11 * js0_1 + J12 * js0_2;
    float s11 = J11 * js1_1 + J12 * js1_2 + COV_BLUR;

    float det = s00 * s11 - s01 * s01;
    float invdet = 1.0f / det;
    float caS  = s11 * invdet * S_SCALE;            // pre-scaled conic
    float ccS  = s00 * invdet * S_SCALE;
    float cb2S = -2.0f * s01 * invdet * S_SCALE;

    float a = fminf(fmaxf(aRaw, 0.0f), 1.0f);
    if (!(tz > NEAR)) a = 0.0f;             // fold 'valid' mask into alpha
    float l2a  = __log2f(a);                // a=0 -> -inf -> exp2 = 0, masked
    float qlim = QLIM + l2a;                // q' + l2a >= qlim  <=>  q <= 9

    float4* dst = (float4*)(sorted + rank * PT_STRIDE);
    dst[0] = make_float4(tz, u, v, caS);
    dst[1] = make_float4(cb2S, ccS, qlim, colR);
    dst[2] = make_float4(colG, colB, l2a, 0.0f);
}

// ---------------------------------------------------------------------------
// Kernel 2: composite + fused combine.  512 blocks (2/CU, __launch_bounds__
// (256,2) guarantees full co-residency -> spin cannot deadlock).
//   a) composite its (strip, chunk) as before, write partials;
//   b) release: __threadfence() all threads, __syncthreads(), tid0 atomicAdd
//      on the arrival counter (device-scope, canonical threadFenceReduction
//      pattern -- graph-capture-safe, unlike cooperative grid.sync which
//      broke correctness in R2);
//   c) the 64 blocks with linear id < 64 acquire-spin until all 512 arrived,
//      then fold the NCHUNK partials per pixel in depth order -> output.
// Saves one kernel launch + one graph-node gap vs the 3-kernel version.
// ---------------------------------------------------------------------------
__global__ __launch_bounds__(CBLK, 2) void k_composite(
    const float* __restrict__ sorted,
    float* __restrict__ partials,
    float* __restrict__ out,
    unsigned int* __restrict__ ctr)
{
    int chunk = blockIdx.y;
    int tid = threadIdx.x;
    int pix = blockIdx.x * CBLK + tid;             // 0..4095: cols x rows 0..31

    __shared__ float4 sg[CHUNK_SZ * 3];            // 1.5 KB
    const float4* src = (const float4*)sorted + chunk * CHUNK_SZ * 3;
    if (tid < CHUNK_SZ * 3) sg[tid] = src[tid];
    __syncthreads();

    float px  = (float)(pix & (IMG_W - 1)) + 0.5f;
    float py0 = (float)(pix >> 7) + 0.5f;

    float T[PXS], cr[PXS], cg[PXS], cb[PXS];
    #pragma unroll
    for (int s = 0; s < PXS; s++) { T[s] = 1.0f; cr[s] = cg[s] = cb[s] = 0.0f; }

    #pragma unroll
    for (int k = 0; k < CHUNK_SZ; k++) {
        float4 A = sg[3 * k + 0];   // tz, u, v, ca'
        float4 B = sg[3 * k + 1];   // 2cb', cc', qlim, colR
        float4 C = sg[3 * k + 2];   // colG, colB, log2a, 0
        float dx    = px - A.y;
        float cadxx = fmaf(A.w * dx, dx, C.z);     // ca'*dx^2 + log2a
        float cb2dx = B.x * dx;
        #pragma unroll
        for (int s = 0; s < PXS; s++) {
            float dy  = py0 + 32.0f * s - A.z;
            float inr = fmaf(B.y, dy, cb2dx);      // cc'*dy + 2cb'*dx
            float qq  = fmaf(dy, inr, cadxx);      // -q/(2ln2) + log2a
            float e   = exp2f(qq);                 // a * exp(-q/2)
            float apx = (qq >= B.z) ? e : 0.0f;    // 3-sigma cutoff vs qlim
            float w = T[s] * apx;
            cr[s] = fmaf(w, B.w, cr[s]);
            cg[s] = fmaf(w, C.x, cg[s]);
            cb[s] = fmaf(w, C.y, cb[s]);
            T[s]  = fmaf(-apx, T[s], T[s]);
        }
    }

    float4* p4 = (float4*)partials;
    #pragma unroll
    for (int s = 0; s < PXS; s++)
        p4[chunk * NPIX + pix + s * ROWSTEP] = make_float4(cr[s], cg[s], cb[s], T[s]);

    // ---- release: make this block's partials visible device-wide ----------
    __threadfence();
    __syncthreads();
    if (tid == 0) atomicAdd(ctr, 1u);

    // ---- 64 combine blocks: acquire-spin for all 512 arrivals -------------
    int lb = blockIdx.y * NSTRIP + blockIdx.x;
    if (lb < NCOMB) {
        if (tid == 0) {
            while (__hip_atomic_load(ctr, __ATOMIC_ACQUIRE,
                                     __HIP_MEMORY_SCOPE_AGENT) < (unsigned)NBLK)
                __builtin_amdgcn_s_sleep(1);
        }
        __syncthreads();

        int I = lb * 256 + tid;                    // 0..16383
        float T2 = 1.0f, r = 0.0f, g = 0.0f, b = 0.0f;
        #pragma unroll
        for (int c = 0; c < NCHUNK; c++) {
            float4 p = ((const float4*)partials)[c * NPIX + I];
            r = fmaf(T2, p.x, r);
            g = fmaf(T2, p.y, g);
            b = fmaf(T2, p.z, b);
            T2 *= p.w;
        }
        out[0 * NPIX + I] = r;
        out[1 * NPIX + I] = g;
        out[2 * NPIX + I] = b;
    }
}

extern "C" void kernel_launch(void* const* d_in, const int* in_sizes, int n_in,
                              void* d_out, int out_size, void* d_ws, size_t ws_size,
                              hipStream_t stream)
{
    const float* coords = (const float*)d_in[0];
    const float* covs   = (const float*)d_in[1];
    const float* colors = (const float*)d_in[2];
    const float* alphas = (const float*)d_in[3];
    const float* Wm     = (const float*)d_in[4];
    const float* Km     = (const float*)d_in[5];

    float* ws = (float*)d_ws;
    float* sorted   = ws;                          // 1024*12 floats = 48 KB
    float* partials = ws + N_PTS * PT_STRIDE;      // 32*16384*4 floats = 8 MB
    unsigned int* ctr = (unsigned int*)(partials + NCHUNK * NPIX * 4);

    k_sortpre<<<dim3(N_PTS / 256), dim3(256), 0, stream>>>(
        coords, covs, colors, alphas, Wm, Km, sorted, ctr);
    k_composite<<<dim3(NSTRIP, NCHUNK), dim3(CBLK), 0, stream>>>(
        sorted, partials, (float*)d_out, ctr);
}

// Round 5
// 97.617 us; speedup vs baseline: 1.5523x; 1.5523x over previous
//
#include <hip/hip_runtime.h>

#define N_PTS   1024
#define IMG_H   128
#define IMG_W   128
#define NPIX    (IMG_H * IMG_W)
#define NEAR    0.01f
#define COV_BLUR 0.3f
#define NCHUNK  32
#define CHUNK_SZ (N_PTS / NCHUNK)     // 32 gaussians per chunk
#define PT_STRIDE 12                  // floats per point record (3 x float4)
#define PXS     4                     // pixels per thread (rows 32 apart)
#define ROWSTEP (NPIX / PXS)          // 4096
#define CBLK    256                   // composite block size (measured best, r4)
#define NSTRIP  (ROWSTEP / CBLK)      // 16 strips x 32 chunks = 512 blocks

// conic pre-scale: q' = -q/(2 ln2)  ->  exp(-q/2) == exp2(q'); 3-sigma: q' >= QLIM
#define S_SCALE (-0.72134752044448170368f)
#define QLIM    (-6.49212768400033533312f)

// NOTE (R2/R4 lessons): do NOT fuse these dispatches.  Cooperative grid.sync
// breaks under the harness's graph capture (R2: absmax 0.9); a spin/atomic
// global barrier inside one dispatch nukes per-XCD L2 via acquire-polling
// (R4: k_composite 2.5us -> 70us).  Three small dispatches is the floor.

// ---------------------------------------------------------------------------
// Kernel 1: fused preprocess + stable depth sort.  4 blocks x 256 threads.
// Coords staged to LDS with coalesced float4 loads.  Stable sort key packed
// as u64 = (sortable_uint(depth) << 10) | index, so the rank scan is ONE
// u64 compare per element.  Keys written from one code site -> bit-identical
// ranking chip-wide.  Uncoalesced cov/color/alpha loads issued BEFORE the
// rank scan so cold-HBM latency hides under its VALU.
// Record (alpha folded into exponent):
//   A=[tz, u, v, ca'] B=[2cb', cc', qlim, colR] C=[colG, colB, log2a, 0]
//   where qlim = QLIM + log2(a); apx = exp2(q' + log2 a) needs no a*e mul.
// ---------------------------------------------------------------------------
__global__ __launch_bounds__(256) void k_sortpre(
    const float* __restrict__ coords,
    const float* __restrict__ covs,
    const float* __restrict__ colors,
    const float* __restrict__ alphas,
    const float* __restrict__ Wm,
    const float* __restrict__ Km,
    float* __restrict__ sorted)
{
    __shared__ __align__(16) float scoord[N_PTS * 3];            // 12 KB
    __shared__ __align__(16) unsigned long long skey[N_PTS];     // 8 KB
    int tid = threadIdx.x;

    // stage all 1024x3 coords coalesced: 768 float4, 3 per thread
    {
        float4* sc4 = (float4*)scoord;
        const float4* g4 = (const float4*)coords;
        #pragma unroll
        for (int j = 0; j < 3; j++) sc4[tid + j * 256] = g4[tid + j * 256];
    }

    float R[3][3], tv[3];
    #pragma unroll
    for (int r = 0; r < 3; r++) {
        #pragma unroll
        for (int c = 0; c < 3; c++) R[r][c] = Wm[r * 4 + c];
        tv[r] = Wm[r * 4 + 3];
    }
    float fx = Km[0], fy = Km[4], cx = Km[2], cy = Km[5];

    __syncthreads();

    // all 1024 stable sort keys -> LDS (single source of truth for ordering)
    #pragma unroll
    for (int q = 0; q < 4; q++) {
        int j = tid + q * 256;
        float c0 = scoord[3 * j], c1 = scoord[3 * j + 1], c2 = scoord[3 * j + 2];
        float d = R[2][0] * c0 + R[2][1] * c1 + R[2][2] * c2 + tv[2];
        unsigned int b = __float_as_uint(d);
        b ^= ((unsigned int)((int)b >> 31)) | 0x80000000u;       // monotone map
        skey[j] = ((unsigned long long)b << 10) | (unsigned int)j;
    }
    __syncthreads();

    int i = blockIdx.x * 256 + tid;

    // issue all uncoalesced global loads NOW; latency hides under rank scan
    float S[3][3];
    #pragma unroll
    for (int r = 0; r < 3; r++)
        #pragma unroll
        for (int c = 0; c < 3; c++) S[r][c] = covs[i * 9 + r * 3 + c];
    float colR = colors[3 * i + 0];
    float colG = colors[3 * i + 1];
    float colB = colors[3 * i + 2];
    float aRaw = alphas[i];

    float c0 = scoord[3 * i], c1 = scoord[3 * i + 1], c2 = scoord[3 * i + 2];
    float tz = R[2][0] * c0 + R[2][1] * c1 + R[2][2] * c2 + tv[2];
    unsigned long long mykey = skey[i];

    // stable rank count: one u64 compare per element
    int rank = 0;
    const ulonglong2* sk2 = (const ulonglong2*)skey;
    #pragma unroll 16
    for (int jj = 0; jj < N_PTS / 2; jj++) {
        ulonglong2 k2 = sk2[jj];
        rank += (k2.x < mykey);
        rank += (k2.y < mykey);
    }

    // full preprocess for own point
    float tx = R[0][0] * c0 + R[0][1] * c1 + R[0][2] * c2 + tv[0];
    float ty = R[1][0] * c0 + R[1][1] * c1 + R[1][2] * c2 + tv[1];

    float invz = 1.0f / fmaxf(tz, NEAR);
    float u = fx * tx * invz + cx;
    float v = fy * ty * invz + cy;
    float J00 = fx * invz;
    float J02 = -fx * tx * invz * invz;
    float J11 = fy * invz;
    float J12 = -fy * ty * invz * invz;

    float M[3][3];
    #pragma unroll
    for (int r = 0; r < 3; r++)
        #pragma unroll
        for (int c = 0; c < 3; c++)
            M[r][c] = R[r][0] * S[0][c] + R[r][1] * S[1][c] + R[r][2] * S[2][c];
    float Sc[3][3];
    #pragma unroll
    for (int r = 0; r < 3; r++)
        #pragma unroll
        for (int c = 0; c < 3; c++)
            Sc[r][c] = M[r][0] * R[c][0] + M[r][1] * R[c][1] + M[r][2] * R[c][2];

    float js0_0 = J00 * Sc[0][0] + J02 * Sc[2][0];
    float js0_1 = J00 * Sc[0][1] + J02 * Sc[2][1];
    float js0_2 = J00 * Sc[0][2] + J02 * Sc[2][2];
    float js1_1 = J11 * Sc[1][1] + J12 * Sc[2][1];
    float js1_2 = J11 * Sc[1][2] + J12 * Sc[2][2];

    float s00 = J00 * js0_0 + J02 * js0_2 + COV_BLUR;
    float s01 = J11 * js0_1 + J12 * js0_2;
    float s11 = J11 * js1_1 + J12 * js1_2 + COV_BLUR;

    float det = s00 * s11 - s01 * s01;
    float invdet = 1.0f / det;
    float caS  = s11 * invdet * S_SCALE;            // pre-scaled conic
    float ccS  = s00 * invdet * S_SCALE;
    float cb2S = -2.0f * s01 * invdet * S_SCALE;

    float a = fminf(fmaxf(aRaw, 0.0f), 1.0f);
    if (!(tz > NEAR)) a = 0.0f;             // fold 'valid' mask into alpha
    float l2a  = __log2f(a);                // a=0 -> -inf -> exp2 = 0, masked
    float qlim = QLIM + l2a;                // q' + l2a >= qlim  <=>  q <= 9

    float4* dst = (float4*)(sorted + rank * PT_STRIDE);
    dst[0] = make_float4(tz, u, v, caS);
    dst[1] = make_float4(cb2S, ccS, qlim, colR);
    dst[2] = make_float4(colG, colB, l2a, 0.0f);
}

// ---------------------------------------------------------------------------
// Kernel 2: per-(pixel-quad, chunk) front-to-back compositing of 32 gaussians.
// 4 pixels/thread in one column, rows 32 apart: dx / conic-x terms / log2a
// shared across the quad.  k-loop FULLY unrolled so the compiler can hoist
// ds_read_b128s ahead of consuming FMAs (hide LDS latency at 8 waves/CU).
// Grid: (16 strips, 32 chunks) x 256 -> 512 blocks, 2/CU, 8 waves/CU.
// ---------------------------------------------------------------------------
__global__ __launch_bounds__(CBLK) void k_composite(
    const float* __restrict__ sorted, float* __restrict__ partials)
{
    int chunk = blockIdx.y;
    int pix = blockIdx.x * CBLK + threadIdx.x;     // 0..4095: cols x rows 0..31

    __shared__ float4 sg[CHUNK_SZ * 3];            // 1.5 KB
    const float4* src = (const float4*)sorted + chunk * CHUNK_SZ * 3;
    if (threadIdx.x < CHUNK_SZ * 3) sg[threadIdx.x] = src[threadIdx.x];
    __syncthreads();

    float px  = (float)(pix & (IMG_W - 1)) + 0.5f;
    float py0 = (float)(pix >> 7) + 0.5f;

    float T[PXS], cr[PXS], cg[PXS], cb[PXS];
    #pragma unroll
    for (int s = 0; s < PXS; s++) { T[s] = 1.0f; cr[s] = cg[s] = cb[s] = 0.0f; }

    #pragma unroll
    for (int k = 0; k < CHUNK_SZ; k++) {
        float4 A = sg[3 * k + 0];   // tz, u, v, ca'
        float4 B = sg[3 * k + 1];   // 2cb', cc', qlim, colR
        float4 C = sg[3 * k + 2];   // colG, colB, log2a, 0
        float dx    = px - A.y;
        float cadxx = fmaf(A.w * dx, dx, C.z);     // ca'*dx^2 + log2a
        float cb2dx = B.x * dx;
        #pragma unroll
        for (int s = 0; s < PXS; s++) {
            float dy  = py0 + 32.0f * s - A.z;
            float inr = fmaf(B.y, dy, cb2dx);      // cc'*dy + 2cb'*dx
            float qq  = fmaf(dy, inr, cadxx);      // -q/(2ln2) + log2a
            float e   = exp2f(qq);                 // a * exp(-q/2)
            float apx = (qq >= B.z) ? e : 0.0f;    // 3-sigma cutoff vs qlim
            float w = T[s] * apx;
            cr[s] = fmaf(w, B.w, cr[s]);
            cg[s] = fmaf(w, C.x, cg[s]);
            cb[s] = fmaf(w, C.y, cb[s]);
            T[s]  = fmaf(-apx, T[s], T[s]);
        }
    }

    float4* p4 = (float4*)partials;
    #pragma unroll
    for (int s = 0; s < PXS; s++)
        p4[chunk * NPIX + pix + s * ROWSTEP] = make_float4(cr[s], cg[s], cb[s], T[s]);
}

// ---------------------------------------------------------------------------
// Kernel 3: fold the NCHUNK partials per pixel in depth order, emit fp32 CHW.
// Split 2 threads/pixel: the fold is associative --
//   (rgbA,TA) + (rgbB,TB) -> (rgbA + TA*rgbB, TA*TB)
// so front half (chunks 0-15) and back half (16-31) fold in parallel and
// merge through LDS.  128 blocks (was 64), half the serial chain per thread.
// Partial slot index IS the image pixel index (identity mapping, r4/r7).
// ---------------------------------------------------------------------------
__global__ __launch_bounds__(256) void k_combine(
    const float* __restrict__ partials, float* __restrict__ out)
{
    __shared__ float4 sseg[128];
    int tid  = threadIdx.x;
    int half = tid >> 7;                           // 0: chunks 0-15, 1: 16-31
    int lane = tid & 127;
    int I = blockIdx.x * 128 + lane;               // pixel 0..16383, 128 blocks

    float T = 1.0f, r = 0.0f, g = 0.0f, b = 0.0f;
    int c0 = half * (NCHUNK / 2);
    #pragma unroll
    for (int c = 0; c < NCHUNK / 2; c++) {
        float4 p = ((const float4*)partials)[(c0 + c) * NPIX + I];
        r = fmaf(T, p.x, r);
        g = fmaf(T, p.y, g);
        b = fmaf(T, p.z, b);
        T *= p.w;
    }
    if (half == 1) sseg[lane] = make_float4(r, g, b, T);
    __syncthreads();
    if (half == 0) {
        float4 s = sseg[lane];
        r = fmaf(T, s.x, r);
        g = fmaf(T, s.y, g);
        b = fmaf(T, s.z, b);
        out[0 * NPIX + I] = r;
        out[1 * NPIX + I] = g;
        out[2 * NPIX + I] = b;
    }
}

extern "C" void kernel_launch(void* const* d_in, const int* in_sizes, int n_in,
                              void* d_out, int out_size, void* d_ws, size_t ws_size,
                              hipStream_t stream)
{
    const float* coords = (const float*)d_in[0];
    const float* covs   = (const float*)d_in[1];
    const float* colors = (const float*)d_in[2];
    const float* alphas = (const float*)d_in[3];
    const float* Wm     = (const float*)d_in[4];
    const float* Km     = (const float*)d_in[5];

    float* ws = (float*)d_ws;
    float* sorted   = ws;                          // 1024*12 floats = 48 KB
    float* partials = ws + N_PTS * PT_STRIDE;      // 32*16384*4 floats = 8 MB

    k_sortpre<<<dim3(N_PTS / 256), dim3(256), 0, stream>>>(
        coords, covs, colors, alphas, Wm, Km, sorted);
    k_composite<<<dim3(NSTRIP, NCHUNK), dim3(CBLK), 0, stream>>>(sorted, partials);
    k_combine<<<dim3(NPIX / 128), dim3(256), 0, stream>>>(partials, (float*)d_out);
}